// Round 4
// baseline (238.105 us; speedup 1.0000x reference)
//
#include <hip/hip_runtime.h>
#include <hip/hip_bf16.h>
#include <cstdint>
#include <cstddef>

#define BB 256
#define RR 512
#define AA 196
#define VV 10000
#define MATT (BB*AA)   // 50176
#define NT13 13        // 13*16 = 208 padded attention cols

typedef float f32x4 __attribute__((ext_vector_type(4)));
typedef __bf16 bf16x8 __attribute__((ext_vector_type(8)));
typedef __bf16 bf16x4 __attribute__((ext_vector_type(4)));

#define MFMA16(a,b,c) __builtin_amdgcn_mfma_f32_16x16x32_bf16(a,b,c,0,0,0)

__device__ __forceinline__ float fast_tanh(float x){
  float ax = fabsf(x);
  float e = __expf(-2.0f*ax);
  float t = __fdividef(1.0f - e, 1.0f + e);
  return x < 0.0f ? -t : t;
}

__device__ __forceinline__ bf16x8 ldfrag_f32(const float* p){
  const float4* q = (const float4*)p;
  float4 f0 = q[0];
  float4 f1 = q[1];
  bf16x8 r;
  r[0]=(__bf16)f0.x; r[1]=(__bf16)f0.y; r[2]=(__bf16)f0.z; r[3]=(__bf16)f0.w;
  r[4]=(__bf16)f1.x; r[5]=(__bf16)f1.y; r[6]=(__bf16)f1.z; r[7]=(__bf16)f1.w;
  return r;
}
__device__ __forceinline__ bf16x8 ldfrag_bf(const __bf16* p){
  return *(const bf16x8*)p;
}

// async global -> LDS, 16B per lane (wave-uniform LDS base + lane*16)
__device__ __forceinline__ void gload16(const void* gsrc, void* ldsdst){
  __builtin_amdgcn_global_load_lds(
      (const __attribute__((address_space(1))) unsigned int*)gsrc,
      (__attribute__((address_space(3))) unsigned int*)ldsdst,
      16, 0, 0);
}

// ---------- weight prep ----------
__global__ void cvt_k(const float* __restrict__ src, __bf16* __restrict__ dst, int n){
  int i = blockIdx.x*256 + threadIdx.x;
  if (i < n) dst[i] = (__bf16)src[i];
}

// vectorized f32 -> bf16, n4 = n/4
__global__ void cvt4_k(const float* __restrict__ src, __bf16* __restrict__ dst, int n4){
  int i = blockIdx.x*256 + threadIdx.x;
  if (i < n4){
    float4 v = ((const float4*)src)[i];
    bf16x4 o;
    o[0]=(__bf16)v.x; o[1]=(__bf16)v.y; o[2]=(__bf16)v.z; o[3]=(__bf16)v.w;
    ((bf16x4*)dst)[i] = o;
  }
}

// Wa2a -> [208][512] bf16, rows 196..207 zero
__global__ void cvt_pad_k(const float* __restrict__ src, __bf16* __restrict__ dst){
  int i = blockIdx.x*256 + threadIdx.x;   // < 208*512
  int row = i >> 9, k = i & 511;
  dst[i] = (__bf16)((row < AA) ? src[row*512 + k] : 0.0f);
}

__global__ void wcat2_k(const float* __restrict__ Wi2h, const float* __restrict__ Wh2h,
                        const float* __restrict__ Wr2a, __bf16* __restrict__ Wcat){
  int k = blockIdx.x*256 + threadIdx.x;   // 0..1535
  int n = blockIdx.y;                     // 0..2047
  float v;
  if (k < 512)       v = Wi2h[n*512 + k];
  else if (k < 1024) v = Wh2h[n*512 + (k-512)];
  else               v = Wr2a[n*512 + (k-1024)];
  Wcat[(size_t)n*1536 + k] = (__bf16)v;
}

__global__ void build_small_k(const float* __restrict__ ba2a, const float* __restrict__ wd2d,
                              const float* __restrict__ bi2h, const float* __restrict__ bh2h,
                              const float* __restrict__ br2a,
                              float* __restrict__ ba_pad, float* __restrict__ wd_pad,
                              float* __restrict__ bcat){
  int i = blockIdx.x*256 + threadIdx.x;
  if (i < 2048){
    bcat[i] = bi2h[i] + bh2h[i] + br2a[i];
  } else if (i < 2048+208){
    int j = i - 2048; ba_pad[j] = (j < AA) ? ba2a[j] : 0.0f;
  } else if (i < 2048+416){
    int j = i - 2256; wd_pad[j] = (j < AA) ? wd2d[j] : 0.0f;
  }
}

// ---------- GEMM: C[m][n] = sum_k A[m][k]*W[n][k] + bias[n], BM=32 BN=64 ----------
__global__ __launch_bounds__(256,4) void gemm2_k(
    const float* __restrict__ A, const __bf16* __restrict__ Bw,
    const float* __restrict__ bias, float* __restrict__ C,
    int M, int N, int K)
{
  const int l = threadIdx.x & 63;
  const int w = threadIdx.x >> 6;
  const int l15 = l & 15;
  const int kg = (l >> 4) * 8;
  const int mrow = blockIdx.y*32;
  const int ncol = blockIdx.x*64 + w*16;
  int c0 = ncol + l15;
  int c0c = c0 < N ? c0 : N-1;
  const float*  pa0 = A  + (size_t)(mrow + l15)*K + kg;
  const float*  pa1 = pa0 + (size_t)16*K;
  const __bf16* pb0 = Bw + (size_t)c0c*K + kg;

  f32x4 acc[2] = {};
  #pragma unroll 4
  for (int k = 0; k < K; k += 32){
    bf16x8 a0 = ldfrag_f32(pa0 + k);
    bf16x8 a1 = ldfrag_f32(pa1 + k);
    bf16x8 b0 = ldfrag_bf(pb0 + k);
    acc[0] = MFMA16(a0, b0, acc[0]);
    acc[1] = MFMA16(a1, b0, acc[1]);
  }
  const int rbase = (l >> 4) * 4;
  #pragma unroll
  for (int mt = 0; mt < 2; mt++)
  #pragma unroll
  for (int r = 0; r < 4; r++){
    int row = mrow + mt*16 + rbase + r;
    int col = ncol + l15;
    if (col < N) C[(size_t)row*N + col] = acc[mt][r] + bias[col];
  }
}

// ---------- fused attention score v3: 2-phase pipelined ----------
// Block: 64 rows x 208 cols, 4 waves (wave = 16 rows x 208 cols).
// A: global -> registers (f32->bf16 in reg). B: double-buffered LDS (XOR-swizzled),
// staged with global_load_lds; STAGE(next) -> COMPUTE(cur) -> vmcnt0+barrier.
#define CVT8(a, f0, f1) do { \
  a[0]=(__bf16)(f0).x; a[1]=(__bf16)(f0).y; a[2]=(__bf16)(f0).z; a[3]=(__bf16)(f0).w; \
  a[4]=(__bf16)(f1).x; a[5]=(__bf16)(f1).y; a[6]=(__bf16)(f1).z; a[7]=(__bf16)(f1).w; \
} while(0)

#define STAGE_B(bufarr, kc) do { \
  _Pragma("unroll") \
  for (int i_ = 0; i_ < 7; i_++) gload16(bsrc[i_] + (kc), (bufarr) + bslot[i_]); \
} while(0)

#define LOAD_A(d0,d1,d2,d3, kc) do { \
  d0 = *(const float4*)(pa + (kc)); \
  d1 = *(const float4*)(pa + (kc) + 4); \
  d2 = *(const float4*)(pa + (kc) + 32); \
  d3 = *(const float4*)(pa + (kc) + 36); \
} while(0)

#define COMPUTE_C(bufarr, A0,A1,A2,A3) do { \
  { bf16x8 a_; CVT8(a_, A0, A1); \
    const int sw_ = (g ^ rho) << 3; \
    _Pragma("unroll") \
    for (int nt_ = 0; nt_ < NT13; nt_++){ \
      bf16x8 b_ = *(const bf16x8*)&(bufarr)[nt_*1024 + l15*64 + sw_]; \
      acc[nt_] = MFMA16(a_, b_, acc[nt_]); } } \
  { bf16x8 a_; CVT8(a_, A2, A3); \
    const int sw_ = ((4 + g) ^ rho) << 3; \
    _Pragma("unroll") \
    for (int nt_ = 0; nt_ < NT13; nt_++){ \
      bf16x8 b_ = *(const bf16x8*)&(bufarr)[nt_*1024 + l15*64 + sw_]; \
      acc[nt_] = MFMA16(a_, b_, acc[nt_]); } } \
} while(0)

#define DRAIN_BAR asm volatile("s_waitcnt vmcnt(0)\n\ts_barrier" ::: "memory")

__global__ __launch_bounds__(256,3) void att_score3_k(
    const float* __restrict__ att, const __bf16* __restrict__ Wa2a_p,
    const float* __restrict__ ba_pad, const float* __restrict__ wd_pad,
    const float* __restrict__ att_h, float* __restrict__ score)
{
  __shared__ __bf16 Bsh0[208*64];   // 26 KB
  __shared__ __bf16 Bsh1[208*64];   // 26 KB
  const int t = threadIdx.x;
  const int l = t & 63;
  const int w = t >> 6;
  const int l15 = l & 15;
  const int g  = l >> 4;
  const int rho = l15 & 7;
  const int rowbase = blockIdx.x * 64;

  // B staging: 26 slot-groups of 64x16B; 7 per wave (waves 2,3 duplicate 24,25 - benign)
  const __bf16* bsrc[7]; int bslot[7];
  #pragma unroll
  for (int i = 0; i < 7; i++){
    int id = i*4 + w;
    if (id >= 26) id -= 2;
    int slotbase = id*64;
    int slot = slotbase + l;
    int row = slot >> 3;
    int j   = slot & 7;
    bslot[i] = slotbase*8;
    bsrc[i]  = Wa2a_p + (size_t)row*RR + ((j ^ (row&7))<<3);
  }

  // A direct: lane (g,l15) covers att[rowbase + w*16 + l15][kc + s*32 + g*8 + 0..7]
  const float* pa = att + (size_t)(rowbase + w*16 + l15)*RR + g*8;

  f32x4 acc[NT13] = {};
  float4 a0,a1,a2,a3, b0,b1,b2,b3;

  STAGE_B(Bsh0, 0); LOAD_A(a0,a1,a2,a3, 0);
  DRAIN_BAR;
  #pragma unroll
  for (int c = 0; c < 8; c += 2){
    STAGE_B(Bsh1, (c+1)*64); LOAD_A(b0,b1,b2,b3, (c+1)*64);
    COMPUTE_C(Bsh0, a0,a1,a2,a3);
    DRAIN_BAR;
    if (c+2 < 8){ STAGE_B(Bsh0, (c+2)*64); LOAD_A(a0,a1,a2,a3, (c+2)*64); }
    COMPUTE_C(Bsh1, b0,b1,b2,b3);
    if (c+2 < 8) DRAIN_BAR;
  }

  // ---- fused epilogue: tanh(acc + ba + att_h) . wd2d, both layers ----
  float wdv[NT13], bav[NT13];
  #pragma unroll
  for (int nt = 0; nt < NT13; nt++){
    int col = nt*16 + l15;
    wdv[nt] = wd_pad[col];
    bav[nt] = ba_pad[col];
  }
  #pragma unroll
  for (int r = 0; r < 4; r++){
    int row = rowbase + w*16 + g*4 + r;
    float ah0 = att_h[row];
    float ah1 = att_h[MATT + row];
    float s0 = 0.0f, s1 = 0.0f;
    #pragma unroll
    for (int nt = 0; nt < NT13; nt++){
      float v = acc[nt][r] + bav[nt];
      s0 += fast_tanh(v + ah0) * wdv[nt];
      s1 += fast_tanh(v + ah1) * wdv[nt];
    }
    #pragma unroll
    for (int o = 1; o < 16; o <<= 1){
      s0 += __shfl_xor(s0, o, 16);
      s1 += __shfl_xor(s1, o, 16);
    }
    if (l15 == 0){
      score[row] = s0;
      score[MATT + row] = s1;
    }
  }
}

// ---------- softmax over 196 positions, one wave per (layer,b) ----------
__global__ void softmax196_k(const float* __restrict__ score, float* __restrict__ wsm){
  int lb = blockIdx.x;          // l*256 + b
  int t = threadIdx.x;          // 64
  const float* s = score + (size_t)lb*AA;
  float v0 = (t      < AA) ? s[t]       : -3.4e38f;
  float v1 = (t+64   < AA) ? s[t+64]    : -3.4e38f;
  float v2 = (t+128  < AA) ? s[t+128]   : -3.4e38f;
  float v3 = (t+192  < AA) ? s[t+192]   : -3.4e38f;
  float mx = fmaxf(fmaxf(v0,v1), fmaxf(v2,v3));
  #pragma unroll
  for (int o = 1; o < 64; o <<= 1) mx = fmaxf(mx, __shfl_xor(mx, o, 64));
  float e0 = (t      < AA) ? __expf(v0 - mx) : 0.0f;
  float e1 = (t+64   < AA) ? __expf(v1 - mx) : 0.0f;
  float e2 = (t+128  < AA) ? __expf(v2 - mx) : 0.0f;
  float e3 = (t+192  < AA) ? __expf(v3 - mx) : 0.0f;
  float sum = e0+e1+e2+e3;
  #pragma unroll
  for (int o = 1; o < 64; o <<= 1) sum += __shfl_xor(sum, o, 64);
  float inv = 1.0f / sum;
  float* o_ = wsm + (size_t)lb*AA;
  if (t      < AA) o_[t]     = e0*inv;
  if (t+64   < AA) o_[t+64]  = e1*inv;
  if (t+128  < AA) o_[t+128] = e2*inv;
  if (t+192  < AA) o_[t+192] = e3*inv;
}

// ---------- att_res for both layers + Xcat fill (merged) ----------
__global__ void attres2_k(const float* __restrict__ att, const float* __restrict__ wsm,
                          const float* __restrict__ x, const float* __restrict__ inputs,
                          float* __restrict__ Xcat0, float* __restrict__ Xcat1){
  int b = blockIdx.x, t = threadIdx.x;  // 512 threads, t = r
  __shared__ float w0[AA], w1[AA];
  if (t < AA) w0[t] = wsm[(size_t)b*AA + t];
  int t2 = t - 256;
  if (t2 >= 0 && t2 < AA) w1[t2] = wsm[(size_t)(256+b)*AA + t2];
  // merged xcatfill (independent of the reduction)
  Xcat0[(size_t)b*1536 + t]       = x[(size_t)b*512 + t];
  Xcat0[(size_t)b*1536 + 512 + t] = inputs[(size_t)1*131072 + b*512 + t];
  Xcat1[(size_t)b*1536 + 512 + t] = inputs[(size_t)3*131072 + b*512 + t];
  __syncthreads();
  const float* ap = att + (size_t)b*AA*RR + t;
  float s00=0, s01=0, s10=0, s11=0;
  #pragma unroll 2
  for (int i = 0; i < AA; i += 2){
    float x0 = ap[(size_t)i*RR];
    float x1 = ap[(size_t)(i+1)*RR];
    s00 += w0[i]*x0;   s10 += w1[i]*x0;
    s01 += w0[i+1]*x1; s11 += w1[i+1]*x1;
  }
  Xcat0[(size_t)b*1536 + 1024 + t] = s00 + s01;
  Xcat1[(size_t)b*1536 + 1024 + t] = s10 + s11;
}

// ---------- LSTM gates ----------
__global__ void gate_k(const float* __restrict__ sums, const float* __restrict__ prev_c,
                       float* __restrict__ out_c, float* __restrict__ out_h,
                       float* __restrict__ hdst, int hstride){
  int idx = blockIdx.x*256 + threadIdx.x;  // < 131072
  int b = idx >> 9, r = idx & 511;
  const float* s = sums + (size_t)b*2048;
  float ig = 1.0f/(1.0f + __expf(-s[r]));
  float fg = 1.0f/(1.0f + __expf(-s[512+r]));
  float og = 1.0f/(1.0f + __expf(-s[1024+r]));
  float g  = fast_tanh(s[1536+r]);
  float c = fg*prev_c[idx] + ig*g;
  float h = og*fast_tanh(c);
  out_c[idx] = c;
  out_h[idx] = h;
  hdst[(size_t)b*hstride + r] = h;
}

// ---------- log_softmax over V=10000, one block per b ----------
__global__ void logsoftmax_k(const float* __restrict__ logits, float* __restrict__ out){
  int b = blockIdx.x, t = threadIdx.x;  // 256 threads
  __shared__ float red[4], red2[4];
  const float* p = logits + (size_t)b*VV;
  float mx = -3.4e38f;
  for (int i = t; i < VV; i += 256) mx = fmaxf(mx, p[i]);
  #pragma unroll
  for (int o = 1; o < 64; o <<= 1) mx = fmaxf(mx, __shfl_xor(mx, o, 64));
  if ((t & 63) == 0) red[t >> 6] = mx;
  __syncthreads();
  mx = fmaxf(fmaxf(red[0], red[1]), fmaxf(red[2], red[3]));
  float sum = 0.0f;
  for (int i = t; i < VV; i += 256) sum += __expf(p[i] - mx);
  #pragma unroll
  for (int o = 1; o < 64; o <<= 1) sum += __shfl_xor(sum, o, 64);
  if ((t & 63) == 0) red2[t >> 6] = sum;
  __syncthreads();
  sum = red2[0] + red2[1] + red2[2] + red2[3];
  float lse = mx + logf(sum);
  float* q = out + (size_t)b*VV;
  for (int i = t; i < VV; i += 256) q[i] = p[i] - lse;
}

extern "C" void kernel_launch(void* const* d_in, const int* in_sizes, int n_in,
                              void* d_out_, int out_size, void* d_ws, size_t ws_size,
                              hipStream_t stream){
  const float* x     = (const float*)d_in[0];
  const float* att   = (const float*)d_in[1];
  const float* inputs= (const float*)d_in[2];
  const float* Wa2a  = (const float*)d_in[3];
  const float* ba2a  = (const float*)d_in[4];
  const float* Wh2a  = (const float*)d_in[5];
  const float* bh2a  = (const float*)d_in[6];
  const float* wd2d  = (const float*)d_in[7];
  // d_in[8] = bd2d : uniform pre-softmax scalar -> softmax-invariant, unused
  const float* Wi2h  = (const float*)d_in[9];
  const float* bi2h  = (const float*)d_in[10];
  const float* Wh2h  = (const float*)d_in[11];
  const float* bh2h  = (const float*)d_in[12];
  const float* Wr2a  = (const float*)d_in[13];
  const float* br2a  = (const float*)d_in[14];
  const float* Wproj = (const float*)d_in[15];
  const float* bproj = (const float*)d_in[16];
  float* d_out = (float*)d_out_;

  char* wsp = (char*)d_ws;
  auto alloc = [&](size_t bytes)->char*{
    char* p = wsp;
    wsp += (bytes + 255) & ~(size_t)255;
    return p;
  };
  __bf16* Wa2a_p   = (__bf16*)alloc((size_t)208*RR*2);   // zero-padded rows
  __bf16* Wh2a_bf  = (__bf16*)alloc((size_t)AA*RR*2);
  __bf16* Wcat_bf  = (__bf16*)alloc((size_t)2048*1536*2);
  __bf16* Wproj_bf = (__bf16*)alloc((size_t)VV*RR*2);
  float* ba_pad = (float*)alloc(208*4);
  float* wd_pad = (float*)alloc(208*4);
  float* bcat   = (float*)alloc(2048*4);
  float* att_h  = (float*)alloc((size_t)2*MATT*4);
  float* score  = (float*)alloc((size_t)2*MATT*4);
  float* wsm    = (float*)alloc((size_t)2*MATT*4);
  float* Xcat0  = (float*)alloc((size_t)BB*1536*4);
  float* Xcat1  = (float*)alloc((size_t)BB*1536*4);
  float* sums   = (float*)alloc((size_t)BB*2048*4);
  float* h1buf  = (float*)alloc((size_t)BB*RR*4);
  float* logits = (float*)alloc((size_t)BB*VV*4);

  // weight prep
  cvt_pad_k<<<(208*RR)/256, 256, 0, stream>>>(Wa2a, Wa2a_p);
  cvt_k<<<(AA*RR+255)/256, 256, 0, stream>>>(Wh2a, Wh2a_bf, AA*RR);
  cvt4_k<<<(VV*RR/4+255)/256, 256, 0, stream>>>(Wproj, Wproj_bf, VV*RR/4);
  wcat2_k<<<dim3(6,2048), 256, 0, stream>>>(Wi2h, Wh2h, Wr2a, Wcat_bf);
  build_small_k<<<10, 256, 0, stream>>>(ba2a, wd2d, bi2h, bh2h, br2a, ba_pad, wd_pad, bcat);

  // attention precompute (att_h depends only on fixed inputs, both layers)
  gemm2_k<<<dim3(4,8), 256, 0, stream>>>(inputs + 1*131072, Wh2a_bf, bh2a, att_h,        256, AA, 512);
  gemm2_k<<<dim3(4,8), 256, 0, stream>>>(inputs + 3*131072, Wh2a_bf, bh2a, att_h + MATT, 256, AA, 512);
  att_score3_k<<<784, 256, 0, stream>>>(att, Wa2a_p, ba_pad, wd_pad, att_h, score);
  softmax196_k<<<512, 64, 0, stream>>>(score, wsm);
  attres2_k<<<256, 512, 0, stream>>>(att, wsm, x, inputs, Xcat0, Xcat1);

  // layer 0
  gemm2_k<<<dim3(32,8), 256, 0, stream>>>(Xcat0, Wcat_bf, bcat, sums, 256, 2048, 1536);
  gate_k<<<512, 256, 0, stream>>>(sums, inputs, d_out, d_out + 131072, Xcat1, 1536);
  // layer 1
  gemm2_k<<<dim3(32,8), 256, 0, stream>>>(Xcat1, Wcat_bf, bcat, sums, 256, 2048, 1536);
  gate_k<<<512, 256, 0, stream>>>(sums, inputs + 2*131072, d_out + 2*131072, d_out + 3*131072, h1buf, 512);

  // projection + log_softmax
  gemm2_k<<<dim3(157,8), 256, 0, stream>>>(h1buf, Wproj_bf, bproj, logits, 256, VV, 512);
  logsoftmax_k<<<256, 256, 0, stream>>>(logits, d_out + 4*131072);
}

// Round 5
// 166.507 us; speedup vs baseline: 1.4300x; 1.4300x over previous
//
#include <hip/hip_runtime.h>
#include <hip/hip_bf16.h>
#include <cstdint>
#include <cstddef>

#define BB 256
#define RR 512
#define AA 196
#define VV 10000
#define MATT (BB*AA)   // 50176
#define NT13 13        // 13*16 = 208 padded attention cols

typedef float f32x4 __attribute__((ext_vector_type(4)));
typedef __bf16 bf16x8 __attribute__((ext_vector_type(8)));
typedef __bf16 bf16x4 __attribute__((ext_vector_type(4)));

#define MFMA16(a,b,c) __builtin_amdgcn_mfma_f32_16x16x32_bf16(a,b,c,0,0,0)

__device__ __forceinline__ float fast_tanh(float x){
  float ax = fabsf(x);
  float e = __expf(-2.0f*ax);
  float t = __fdividef(1.0f - e, 1.0f + e);
  return x < 0.0f ? -t : t;
}

// async global -> LDS, 16B per lane (LDS dest must be wave-uniform; HW adds lane*16)
__device__ __forceinline__ void gload16(const void* gsrc, void* ldsdst){
  __builtin_amdgcn_global_load_lds(
      (const __attribute__((address_space(1))) unsigned int*)gsrc,
      (__attribute__((address_space(3))) unsigned int*)ldsdst,
      16, 0, 0);
}

#define ABAR   asm volatile("s_barrier" ::: "memory")
#define WVM(N) asm volatile("s_waitcnt vmcnt(" #N ")" ::: "memory")

#define CVT8(a, f0, f1) do { \
  a[0]=(__bf16)(f0).x; a[1]=(__bf16)(f0).y; a[2]=(__bf16)(f0).z; a[3]=(__bf16)(f0).w; \
  a[4]=(__bf16)(f1).x; a[5]=(__bf16)(f1).y; a[6]=(__bf16)(f1).z; a[7]=(__bf16)(f1).w; \
} while(0)

// ---------- weight prep ----------
// f32 -> bf16 vectorized, n4 = n/4
__global__ void cvt4_k(const float* __restrict__ src, __bf16* __restrict__ dst, int n4){
  int i = blockIdx.x*256 + threadIdx.x;
  if (i < n4){
    float4 v = ((const float4*)src)[i];
    bf16x4 o;
    o[0]=(__bf16)v.x; o[1]=(__bf16)v.y; o[2]=(__bf16)v.z; o[3]=(__bf16)v.w;
    ((bf16x4*)dst)[i] = o;
  }
}

// [total][512] bf16, rows >= nvalid zeroed. grid covers total*512.
__global__ void cvt_padrows_k(const float* __restrict__ src, __bf16* __restrict__ dst, int nvalid){
  int i = blockIdx.x*256 + threadIdx.x;
  int row = i >> 9;
  dst[i] = (__bf16)((row < nvalid) ? src[(size_t)row*512 + (i & 511)] : 0.0f);
}

__global__ void wcat2_k(const float* __restrict__ Wi2h, const float* __restrict__ Wh2h,
                        const float* __restrict__ Wr2a, __bf16* __restrict__ Wcat){
  int k = blockIdx.x*256 + threadIdx.x;   // 0..1535
  int n = blockIdx.y;                     // 0..2047
  float v;
  if (k < 512)       v = Wi2h[n*512 + k];
  else if (k < 1024) v = Wh2h[n*512 + (k-512)];
  else               v = Wr2a[n*512 + (k-1024)];
  Wcat[(size_t)n*1536 + k] = (__bf16)v;
}

__global__ void build_small_k(const float* __restrict__ ba2a, const float* __restrict__ wd2d,
                              const float* __restrict__ bi2h, const float* __restrict__ bh2h,
                              const float* __restrict__ br2a,
                              float* __restrict__ ba_pad, float* __restrict__ wd_pad,
                              float* __restrict__ bcat){
  int i = blockIdx.x*256 + threadIdx.x;
  if (i < 2048){
    bcat[i] = bi2h[i] + bh2h[i] + br2a[i];
  } else if (i < 2048+208){
    int j = i - 2048; ba_pad[j] = (j < AA) ? ba2a[j] : 0.0f;
  } else if (i < 2048+416){
    int j = i - 2256; wd_pad[j] = (j < AA) ? wd2d[j] : 0.0f;
  }
}

// ---------- pipelined bf16 GEMM: C[m][n] = sum_k A[m][k]*W[n][k] + bias[n] ----------
// BM=32, BN=64, K-chunk=64, 4 waves, 3-buffer LDS, counted vmcnt (never 0 in steady state).
// A: [M][K] bf16 row-major; Bw: [Npad>=grid.x*64][K] bf16; writes guarded col<N.
__global__ __launch_bounds__(256,4) void gemm3_k(
    const __bf16* __restrict__ A, const __bf16* __restrict__ Bw,
    const float* __restrict__ bias, float* __restrict__ C,
    int N, int K, int NC)
{
  __shared__ __bf16 AshAll[3*2048];   // 3 x 32x64
  __shared__ __bf16 BshAll[3*4096];   // 3 x 64x64
  const int t = threadIdx.x;
  const int l = t & 63;
  const int w = t >> 6;
  const int l15 = l & 15;
  const int g  = l >> 4;
  const int rho = l15 & 7;
  const int mrow = blockIdx.y*32;
  const int ncb  = blockIdx.x*64;

  // staging descriptors: per-lane global src (pre-swizzled), wave-uniform LDS dest
  const int arow = t >> 3, aj = t & 7;             // A slot t: row 0..31, 16B-slot 0..7
  const __bf16* as_ = A + (size_t)(mrow + arow)*K + ((aj ^ (arow&7)) << 3);
  const int aoff = w*512;                          // wave-uniform elems offset (64 slots x 8)
  const __bf16* bs0_ = Bw + (size_t)(ncb + arow)*K      + ((aj ^ (arow&7)) << 3);
  const __bf16* bs1_ = Bw + (size_t)(ncb + 32 + arow)*K + ((aj ^ (arow&7)) << 3);
  const int boff0 = w*512;
  const int boff1 = 2048 + w*512;

#define G3_STAGE(B, CH) do { \
    gload16(as_  + (CH)*64, AshAll + (B)*2048 + aoff); \
    gload16(bs0_ + (CH)*64, BshAll + (B)*4096 + boff0); \
    gload16(bs1_ + (CH)*64, BshAll + (B)*4096 + boff1); \
  } while(0)

  f32x4 acc0 = {}, acc1 = {};

#define G3_COMPUTE(B) do { \
    const __bf16* As_ = AshAll + (B)*2048; \
    const __bf16* Bs_ = BshAll + (B)*4096; \
    _Pragma("unroll") \
    for (int s_ = 0; s_ < 2; s_++){ \
      int q_ = (((s_<<2)+g) ^ rho) << 3; \
      bf16x8 a0_ = *(const bf16x8*)(As_ + l15*64 + q_); \
      bf16x8 a1_ = *(const bf16x8*)(As_ + (l15+16)*64 + q_); \
      bf16x8 b_  = *(const bf16x8*)(Bs_ + (w*16+l15)*64 + q_); \
      acc0 = MFMA16(a0_, b_, acc0); \
      acc1 = MFMA16(a1_, b_, acc1); \
    } \
  } while(0)

  G3_STAGE(0,0); G3_STAGE(1,1); G3_STAGE(2,2);
  WVM(6); ABAR;
  int buf = 0;
  for (int c = 0; c < NC; c++){
    G3_COMPUTE(buf);
    if (c + 3 < NC){
      ABAR;
      G3_STAGE(buf, c+3);
      WVM(6); ABAR;
    } else if (c == NC-3){
      WVM(3); ABAR;
    } else if (c == NC-2){
      WVM(0); ABAR;
    }
    buf = (buf == 2) ? 0 : buf + 1;
  }

  int col = ncb + w*16 + l15;
  if (col < N){
    float bv = bias[col];
    #pragma unroll
    for (int r = 0; r < 4; r++){
      C[(size_t)(mrow + g*4 + r)*N + col]      = acc0[r] + bv;
      C[(size_t)(mrow + 16 + g*4 + r)*N + col] = acc1[r] + bv;
    }
  }
#undef G3_STAGE
#undef G3_COMPUTE
}

// ---------- fused attention score v5: depth-2 counted-vmcnt pipeline ----------
// Block: 64 rows x 208 cols, 4 waves. B: 3-buffer LDS (XOR-swizzled, global_load_lds).
// A: global->regs, 3 register sets. Per iter: COMPUTE(c); bar; STAGE(c+3)+LOADA(c+3); vmcnt(22); bar.
__global__ __launch_bounds__(256,2) void att_score5_k(
    const float* __restrict__ att, const __bf16* __restrict__ Wa2a_p,
    const float* __restrict__ ba_pad, const float* __restrict__ wd_pad,
    const float* __restrict__ att_h, float* __restrict__ score)
{
  __shared__ __bf16 Bsh[3*13312];   // 3 x [208][64], 78 KB
  const int t = threadIdx.x;
  const int l = t & 63;
  const int w = t >> 6;
  const int l15 = l & 15;
  const int g  = l >> 4;
  const int rho = l15 & 7;
  const int rowbase = blockIdx.x * 64;

  // B staging: 26 slot-groups of 64x16B; 7 per wave (waves 2,3 duplicate 24,25 - benign)
  const __bf16* bsrc[7]; int bslot[7];
  #pragma unroll
  for (int i = 0; i < 7; i++){
    int id = i*4 + w;
    if (id >= 26) id -= 2;
    int slotbase = id*64;
    int slot = slotbase + l;
    int row = slot >> 3;
    int j   = slot & 7;
    bslot[i] = slotbase*8;                      // wave-uniform
    bsrc[i]  = Wa2a_p + (size_t)row*RR + ((j ^ (row&7))<<3);
  }

  const float* pa = att + (size_t)(rowbase + w*16 + l15)*RR + g*8;

  f32x4 acc[NT13] = {};
  float4 p00,p01,p02,p03, p10,p11,p12,p13, p20,p21,p22,p23;

#define SC_STAGE(B, KC) do { \
    _Pragma("unroll") \
    for (int i_ = 0; i_ < 7; i_++) gload16(bsrc[i_] + (KC), Bsh + (B)*13312 + bslot[i_]); \
  } while(0)
#define SC_LOADA(S, KC) do { \
    p##S##0 = *(const float4*)(pa + (KC)); \
    p##S##1 = *(const float4*)(pa + (KC) + 4); \
    p##S##2 = *(const float4*)(pa + (KC) + 32); \
    p##S##3 = *(const float4*)(pa + (KC) + 36); \
  } while(0)
#define SC_COMPUTE(B, S) do { \
    { bf16x8 a_; CVT8(a_, p##S##0, p##S##1); \
      const int sw_ = (g ^ rho) << 3; \
      _Pragma("unroll") \
      for (int nt_ = 0; nt_ < NT13; nt_++){ \
        bf16x8 b_ = *(const bf16x8*)&Bsh[(B)*13312 + nt_*1024 + l15*64 + sw_]; \
        acc[nt_] = MFMA16(a_, b_, acc[nt_]); } } \
    { bf16x8 a_; CVT8(a_, p##S##2, p##S##3); \
      const int sw_ = ((4 + g) ^ rho) << 3; \
      _Pragma("unroll") \
      for (int nt_ = 0; nt_ < NT13; nt_++){ \
        bf16x8 b_ = *(const bf16x8*)&Bsh[(B)*13312 + nt_*1024 + l15*64 + sw_]; \
        acc[nt_] = MFMA16(a_, b_, acc[nt_]); } } \
  } while(0)

  SC_STAGE(0,0);   SC_LOADA(0,0);
  SC_STAGE(1,64);  SC_LOADA(1,64);
  SC_STAGE(2,128); SC_LOADA(2,128);
  WVM(22); ABAR;
  SC_COMPUTE(0,0); ABAR; SC_STAGE(0,192); SC_LOADA(0,192); WVM(22); ABAR;  // c=0
  SC_COMPUTE(1,1); ABAR; SC_STAGE(1,256); SC_LOADA(1,256); WVM(22); ABAR;  // c=1
  SC_COMPUTE(2,2); ABAR; SC_STAGE(2,320); SC_LOADA(2,320); WVM(22); ABAR;  // c=2
  SC_COMPUTE(0,0); ABAR; SC_STAGE(0,384); SC_LOADA(0,384); WVM(22); ABAR;  // c=3
  SC_COMPUTE(1,1); ABAR; SC_STAGE(1,448); SC_LOADA(1,448); WVM(22); ABAR;  // c=4
  SC_COMPUTE(2,2); WVM(11); ABAR;                                          // c=5
  SC_COMPUTE(0,0); WVM(0);  ABAR;                                          // c=6
  SC_COMPUTE(1,1);                                                         // c=7

  // ---- fused epilogue: tanh(acc + ba + att_h) . wd2d, both layers ----
  float wdv[NT13], bav[NT13];
  #pragma unroll
  for (int nt = 0; nt < NT13; nt++){
    int col = nt*16 + l15;
    wdv[nt] = wd_pad[col];
    bav[nt] = ba_pad[col];
  }
  #pragma unroll
  for (int r = 0; r < 4; r++){
    int row = rowbase + w*16 + g*4 + r;
    float ah0 = att_h[row];
    float ah1 = att_h[MATT + row];
    float s0 = 0.0f, s1 = 0.0f;
    #pragma unroll
    for (int nt = 0; nt < NT13; nt++){
      float v = acc[nt][r] + bav[nt];
      s0 += fast_tanh(v + ah0) * wdv[nt];
      s1 += fast_tanh(v + ah1) * wdv[nt];
    }
    #pragma unroll
    for (int o = 1; o < 16; o <<= 1){
      s0 += __shfl_xor(s0, o, 16);
      s1 += __shfl_xor(s1, o, 16);
    }
    if (l15 == 0){
      score[row] = s0;
      score[MATT + row] = s1;
    }
  }
#undef SC_STAGE
#undef SC_LOADA
#undef SC_COMPUTE
}

// ---------- softmax over 196 positions, one wave per (layer,b) ----------
__global__ void softmax196_k(const float* __restrict__ score, float* __restrict__ wsm){
  int lb = blockIdx.x;          // l*256 + b
  int t = threadIdx.x;          // 64
  const float* s = score + (size_t)lb*AA;
  float v0 = (t      < AA) ? s[t]       : -3.4e38f;
  float v1 = (t+64   < AA) ? s[t+64]    : -3.4e38f;
  float v2 = (t+128  < AA) ? s[t+128]   : -3.4e38f;
  float v3 = (t+192  < AA) ? s[t+192]   : -3.4e38f;
  float mx = fmaxf(fmaxf(v0,v1), fmaxf(v2,v3));
  #pragma unroll
  for (int o = 1; o < 64; o <<= 1) mx = fmaxf(mx, __shfl_xor(mx, o, 64));
  float e0 = (t      < AA) ? __expf(v0 - mx) : 0.0f;
  float e1 = (t+64   < AA) ? __expf(v1 - mx) : 0.0f;
  float e2 = (t+128  < AA) ? __expf(v2 - mx) : 0.0f;
  float e3 = (t+192  < AA) ? __expf(v3 - mx) : 0.0f;
  float sum = e0+e1+e2+e3;
  #pragma unroll
  for (int o = 1; o < 64; o <<= 1) sum += __shfl_xor(sum, o, 64);
  float inv = 1.0f / sum;
  float* o_ = wsm + (size_t)lb*AA;
  if (t      < AA) o_[t]     = e0*inv;
  if (t+64   < AA) o_[t+64]  = e1*inv;
  if (t+128  < AA) o_[t+128] = e2*inv;
  if (t+192  < AA) o_[t+192] = e3*inv;
}

// ---------- att_res (both layers, float4 + LDS reduce) + Xcat fills, bf16 out ----------
__global__ __launch_bounds__(512) void attres3_k(
    const float* __restrict__ att, const float* __restrict__ wsm,
    const float* __restrict__ x, const float* __restrict__ inputs,
    __bf16* __restrict__ Xcat0, __bf16* __restrict__ Xcat1){
  int b = blockIdx.x, t = threadIdx.x;  // 512 threads
  __shared__ float w0[208], w1[208];
  __shared__ float4 redv[4][128];
  if (t < AA) w0[t] = wsm[(size_t)b*AA + t];
  int t2 = t - 256;
  if (t2 >= 0 && t2 < AA) w1[t2] = wsm[(size_t)(256+b)*AA + t2];
  Xcat0[(size_t)b*1536 + t]       = (__bf16)x[(size_t)b*512 + t];
  Xcat0[(size_t)b*1536 + 512 + t] = (__bf16)inputs[(size_t)1*131072 + b*512 + t];
  Xcat1[(size_t)b*1536 + 512 + t] = (__bf16)inputs[(size_t)3*131072 + b*512 + t];
  __syncthreads();
  int cg = t & 127, ig = t >> 7;
  const float4* ap = (const float4*)(att + (size_t)b*AA*RR) + cg;
  float4 s0 = {0,0,0,0}, s1 = {0,0,0,0};
  #pragma unroll 4
  for (int i = ig; i < AA; i += 4){
    float4 v = ap[(size_t)i*128];
    float a0 = w0[i], a1 = w1[i];
    s0.x += v.x*a0; s0.y += v.y*a0; s0.z += v.z*a0; s0.w += v.w*a0;
    s1.x += v.x*a1; s1.y += v.y*a1; s1.z += v.z*a1; s1.w += v.w*a1;
  }
  redv[ig][cg] = s0; __syncthreads();
  if (t < 128){
    float4 a = redv[0][t], b4 = redv[1][t], c4 = redv[2][t], d4 = redv[3][t];
    __bf16* o = Xcat0 + (size_t)b*1536 + 1024 + t*4;
    o[0]=(__bf16)(a.x+b4.x+c4.x+d4.x); o[1]=(__bf16)(a.y+b4.y+c4.y+d4.y);
    o[2]=(__bf16)(a.z+b4.z+c4.z+d4.z); o[3]=(__bf16)(a.w+b4.w+c4.w+d4.w);
  }
  __syncthreads();
  redv[ig][cg] = s1; __syncthreads();
  if (t < 128){
    float4 a = redv[0][t], b4 = redv[1][t], c4 = redv[2][t], d4 = redv[3][t];
    __bf16* o = Xcat1 + (size_t)b*1536 + 1024 + t*4;
    o[0]=(__bf16)(a.x+b4.x+c4.x+d4.x); o[1]=(__bf16)(a.y+b4.y+c4.y+d4.y);
    o[2]=(__bf16)(a.z+b4.z+c4.z+d4.z); o[3]=(__bf16)(a.w+b4.w+c4.w+d4.w);
  }
}

// ---------- LSTM gates ----------
__global__ void gate_k(const float* __restrict__ sums, const float* __restrict__ prev_c,
                       float* __restrict__ out_c, float* __restrict__ out_h,
                       __bf16* __restrict__ hdst, int hstride){
  int idx = blockIdx.x*256 + threadIdx.x;  // < 131072
  int b = idx >> 9, r = idx & 511;
  const float* s = sums + (size_t)b*2048;
  float ig = 1.0f/(1.0f + __expf(-s[r]));
  float fg = 1.0f/(1.0f + __expf(-s[512+r]));
  float og = 1.0f/(1.0f + __expf(-s[1024+r]));
  float g  = fast_tanh(s[1536+r]);
  float c = fg*prev_c[idx] + ig*g;
  float h = og*fast_tanh(c);
  out_c[idx] = c;
  out_h[idx] = h;
  hdst[(size_t)b*hstride + r] = (__bf16)h;
}

// ---------- log_softmax over V=10000, one block per b ----------
__global__ void logsoftmax_k(const float* __restrict__ logits, float* __restrict__ out){
  int b = blockIdx.x, t = threadIdx.x;  // 256 threads
  __shared__ float red[4], red2[4];
  const float* p = logits + (size_t)b*VV;
  float mx = -3.4e38f;
  for (int i = t; i < VV; i += 256) mx = fmaxf(mx, p[i]);
  #pragma unroll
  for (int o = 1; o < 64; o <<= 1) mx = fmaxf(mx, __shfl_xor(mx, o, 64));
  if ((t & 63) == 0) red[t >> 6] = mx;
  __syncthreads();
  mx = fmaxf(fmaxf(red[0], red[1]), fmaxf(red[2], red[3]));
  float sum = 0.0f;
  for (int i = t; i < VV; i += 256) sum += __expf(p[i] - mx);
  #pragma unroll
  for (int o = 1; o < 64; o <<= 1) sum += __shfl_xor(sum, o, 64);
  if ((t & 63) == 0) red2[t >> 6] = sum;
  __syncthreads();
  sum = red2[0] + red2[1] + red2[2] + red2[3];
  float lse = mx + logf(sum);
  float* q = out + (size_t)b*VV;
  for (int i = t; i < VV; i += 256) q[i] = p[i] - lse;
}

extern "C" void kernel_launch(void* const* d_in, const int* in_sizes, int n_in,
                              void* d_out_, int out_size, void* d_ws, size_t ws_size,
                              hipStream_t stream){
  const float* x     = (const float*)d_in[0];
  const float* att   = (const float*)d_in[1];
  const float* inputs= (const float*)d_in[2];
  const float* Wa2a  = (const float*)d_in[3];
  const float* ba2a  = (const float*)d_in[4];
  const float* Wh2a  = (const float*)d_in[5];
  const float* bh2a  = (const float*)d_in[6];
  const float* wd2d  = (const float*)d_in[7];
  // d_in[8] = bd2d : uniform pre-softmax scalar -> softmax-invariant, unused
  const float* Wi2h  = (const float*)d_in[9];
  const float* bi2h  = (const float*)d_in[10];
  const float* Wh2h  = (const float*)d_in[11];
  const float* bh2h  = (const float*)d_in[12];
  const float* Wr2a  = (const float*)d_in[13];
  const float* br2a  = (const float*)d_in[14];
  const float* Wproj = (const float*)d_in[15];
  const float* bproj = (const float*)d_in[16];
  float* d_out = (float*)d_out_;

  char* wsp = (char*)d_ws;
  auto alloc = [&](size_t bytes)->char*{
    char* p = wsp;
    wsp += (bytes + 255) & ~(size_t)255;
    return p;
  };
  __bf16* Wa2a_p   = (__bf16*)alloc((size_t)208*RR*2);     // [208][512], zero-pad rows
  __bf16* Wh2a_pad = (__bf16*)alloc((size_t)256*RR*2);     // [256][512], zero-pad rows
  __bf16* Wcat_bf  = (__bf16*)alloc((size_t)2048*1536*2);
  __bf16* Wproj_bf = (__bf16*)alloc((size_t)10048*RR*2);   // [10048][512], zero-pad rows
  __bf16* inp_bf   = (__bf16*)alloc((size_t)512*RR*2);     // [inputs1 ; inputs3] bf16
  float* ba_pad = (float*)alloc(208*4);
  float* wd_pad = (float*)alloc(208*4);
  float* bcat   = (float*)alloc(2048*4);
  float* att_h  = (float*)alloc((size_t)2*MATT*4);
  float* score  = (float*)alloc((size_t)2*MATT*4);
  float* wsm    = (float*)alloc((size_t)2*MATT*4);
  __bf16* Xcat0 = (__bf16*)alloc((size_t)BB*1536*2);
  __bf16* Xcat1 = (__bf16*)alloc((size_t)BB*1536*2);
  float* sums   = (float*)alloc((size_t)BB*2048*4);
  __bf16* h1_bf = (__bf16*)alloc((size_t)BB*RR*2);
  float* logits = (float*)alloc((size_t)BB*VV*4);

  // weight prep
  cvt_padrows_k<<<(208*512)/256, 256, 0, stream>>>(Wa2a, Wa2a_p, AA);
  cvt_padrows_k<<<(256*512)/256, 256, 0, stream>>>(Wh2a, Wh2a_pad, AA);
  cvt_padrows_k<<<(10048*512)/256, 256, 0, stream>>>(Wproj, Wproj_bf, VV);
  cvt4_k<<<(131072/4)/256, 256, 0, stream>>>(inputs + 1*131072, inp_bf, 131072/4);
  cvt4_k<<<(131072/4)/256, 256, 0, stream>>>(inputs + 3*131072, inp_bf + 131072, 131072/4);
  wcat2_k<<<dim3(6,2048), 256, 0, stream>>>(Wi2h, Wh2h, Wr2a, Wcat_bf);
  build_small_k<<<10, 256, 0, stream>>>(ba2a, wd2d, bi2h, bh2h, br2a, ba_pad, wd_pad, bcat);

  // att_h for both layers in one GEMM: [512 rows][196]
  gemm3_k<<<dim3(4,16), 256, 0, stream>>>(inp_bf, Wh2a_pad, bh2a, att_h, AA, 512, 8);
  att_score5_k<<<784, 256, 0, stream>>>(att, Wa2a_p, ba_pad, wd_pad, att_h, score);
  softmax196_k<<<512, 64, 0, stream>>>(score, wsm);
  attres3_k<<<256, 512, 0, stream>>>(att, wsm, x, inputs, Xcat0, Xcat1);

  // layer 0
  gemm3_k<<<dim3(32,8), 256, 0, stream>>>(Xcat0, Wcat_bf, bcat, sums, 2048, 1536, 24);
  gate_k<<<512, 256, 0, stream>>>(sums, inputs, d_out, d_out + 131072, Xcat1, 1536);
  // layer 1
  gemm3_k<<<dim3(32,8), 256, 0, stream>>>(Xcat1, Wcat_bf, bcat, sums, 2048, 1536, 24);
  gate_k<<<512, 256, 0, stream>>>(sums, inputs + 2*131072, d_out + 2*131072, d_out + 3*131072, h1_bf, 512);

  // projection + log_softmax
  gemm3_k<<<dim3(157,8), 256, 0, stream>>>(h1_bf, Wproj_bf, bproj, logits, VV, 512, 8);
  logsoftmax_k<<<256, 256, 0, stream>>>(logits, d_out + 4*131072);
}